// Round 1
// 796.715 us; speedup vs baseline: 1.0078x; 1.0078x over previous
//
#include <hip/hip_runtime.h>

// RelMultiHeadAttention (Transformer-XL) on gfx950.
// B=2, S=2048, D=1024, H=16, hd=64.
// R7: two-strip fused kernel (131.5 KB LDS, 1 block/CU). The rel-shift is
// applied AT WRITE TIME into a second x-strip: x row a stores value x[a][m]
// at column j=(m+a+1)&2047 (row a's tail feeds strip row a, head feeds row
// a-1; rows i0 and i0+16 have disjoint used columns so they share physical
// row 0 -> 16 rows). This removes the f16 LDS read-modify-write scatter and
// the P1->P2 barrier entirely: qk-MFMA and x-MFMA run in ONE phase (32 MFMA
// + 32 global b128 loads of independent work per wave). Softmax folds the
// shift with vectorized reads of both strips + per-element select. V B-frags
// are preloaded into registers under the exp phase. fp32 partials reuse the
// x-strip region. Barriers: 5 -> 3.

typedef float  floatx4 __attribute__((ext_vector_type(4)));
typedef __bf16 bf16x8  __attribute__((ext_vector_type(8)));
typedef _Float16 f16x8 __attribute__((ext_vector_type(8)));
typedef _Float16 f16x4 __attribute__((ext_vector_type(4)));

#define LSTR 40   // proj-GEMM LDS row stride (bf16): conflict-free b128

struct GP {
  const void* A;
  const __bf16* B;
  int lda, ldb, K;
  float* outF;
  __bf16* out1;
  __bf16* out2;
  _Float16* out1h;
  const float* bias;
  const float* rrb;
};

// MODE: 0=Qproj(dual q/qrr) 1=Kproj 2=Vproj(transposed, f16) 3=Rproj 4=OUTproj
template<int MODE, bool AF32>
__global__ void __launch_bounds__(256) gemm_k(GP p) {
  __shared__ __bf16 lA[128 * LSTR];
  __shared__ __bf16 lB[128 * LSTR];
  const int t = threadIdx.x;
  const int wave = t >> 6, lane = t & 63;
  const int m0 = blockIdx.y * 128, n0 = blockIdx.x * 128;
  const int srow = t >> 2, scol = (t & 3) << 3;

  const float*  Af = (const float*)p.A;
  const __bf16* Ab = (const __bf16*)p.A;
  const __bf16* Bb = p.B;

  floatx4 acc[4][4];
#pragma unroll
  for (int i = 0; i < 4; i++)
#pragma unroll
    for (int j = 0; j < 4; j++) acc[i][j] = floatx4{0.f, 0.f, 0.f, 0.f};

  const int lr = lane & 15, lq = lane >> 4;
  const int wr = (wave >> 1) << 6, wc = (wave & 1) << 6;

  for (int kk = 0; kk < p.K; kk += 32) {
#pragma unroll
    for (int h2 = 0; h2 < 2; h2++) {
      int r = srow + (h2 << 6);
      if (AF32) {
        const float* ap = Af + (long)(m0 + r) * p.lda + kk + scol;
        float4 f0 = *(const float4*)ap;
        float4 f1 = *(const float4*)(ap + 4);
        bf16x8 o;
        o[0] = (__bf16)f0.x; o[1] = (__bf16)f0.y; o[2] = (__bf16)f0.z; o[3] = (__bf16)f0.w;
        o[4] = (__bf16)f1.x; o[5] = (__bf16)f1.y; o[6] = (__bf16)f1.z; o[7] = (__bf16)f1.w;
        *(bf16x8*)&lA[r * LSTR + scol] = o;
      } else {
        const __bf16* ap = Ab + (long)(m0 + r) * p.lda + kk + scol;
        *(bf16x8*)&lA[r * LSTR + scol] = *(const bf16x8*)ap;
      }
      const __bf16* bp = Bb + (long)(n0 + r) * p.ldb + kk + scol;
      *(bf16x8*)&lB[r * LSTR + scol] = *(const bf16x8*)bp;
    }
    __syncthreads();
    bf16x8 aF[4], bF[4];
#pragma unroll
    for (int i = 0; i < 4; i++)
      aF[i] = *(bf16x8*)&lA[(wr + i * 16 + lr) * LSTR + (lq << 3)];
#pragma unroll
    for (int i = 0; i < 4; i++)
      bF[i] = *(bf16x8*)&lB[(wc + i * 16 + lr) * LSTR + (lq << 3)];
#pragma unroll
    for (int i = 0; i < 4; i++)
#pragma unroll
      for (int j = 0; j < 4; j++)
        acc[i][j] = __builtin_amdgcn_mfma_f32_16x16x32_bf16(aF[i], bF[j], acc[i][j], 0, 0, 0);
    __syncthreads();
  }

  // C/D layout: col = lane&15, row = (lane>>4)*4 + reg  [measured m89/m91]
#pragma unroll
  for (int i = 0; i < 4; i++) {
#pragma unroll
    for (int j = 0; j < 4; j++) {
      int col = n0 + wc + j * 16 + lr;
#pragma unroll
      for (int g = 0; g < 4; g++) {
        int rl = m0 + wr + i * 16 + (lq << 2) + g;
        float val = acc[i][j][g];
        if constexpr (MODE <= 2) {
          int b = rl >> 11, s = rl & 2047;
          int h = col >> 6, d = col & 63;
          float v = val + p.bias[col];
          if constexpr (MODE == 0) {
            long dst = (((long)(b * 16 + h) * 2048 + s) << 6) + d;
            p.out1[dst] = (__bf16)v;
            p.out2[dst] = (__bf16)(v + p.rrb[col]);
          } else if constexpr (MODE == 1) {
            long dst = (((long)(b * 16 + h) * 2048 + s) << 6) + d;
            p.out1[dst] = (__bf16)v;
          } else {  // V transposed f16: [bh][d][seq]
            long dst = ((((long)(b * 16 + h)) << 6) + d) * 2048 + s;
            p.out1h[dst] = (_Float16)v;
          }
        } else if constexpr (MODE == 3) {
          int h = col >> 6, d = col & 63;
          long dst = (((long)h * 2048 + rl) << 6) + d;
          p.out1[dst] = (__bf16)val;
        } else {  // MODE 4
          p.outF[(long)rl * 1024 + col] = val + p.bias[col];
        }
      }
    }
  }
}

__global__ void __launch_bounds__(256) cb_k(const __bf16* kb, const float* rwb, float* cb) {
  long id = (long)blockIdx.x * 256 + threadIdx.x;  // 32*2048
  int z = (int)(id >> 11);
  int j = (int)(id & 2047);
  int h = z & 15;
  const __bf16* kp = kb + (((long)z * 2048 + j) << 6);
  float s = 0.f;
#pragma unroll
  for (int c = 0; c < 8; c++) {
    bf16x8 kv = *(const bf16x8*)(kp + c * 8);
#pragma unroll
    for (int e = 0; e < 8; e++) s += rwb[h * 64 + c * 8 + e] * (float)kv[e];
  }
  cb[id] = s * 0.125f;
}

__global__ void __launch_bounds__(256) tr_cvt(const float* src, __bf16* dst) {
  __shared__ float tile[64][65];
  int bx = blockIdx.x, by = blockIdx.y;
  int tx = threadIdx.x & 63, ty = threadIdx.x >> 6;
#pragma unroll
  for (int r = ty; r < 64; r += 4)
    tile[r][tx] = src[(long)(by * 64 + r) * 1024 + bx * 64 + tx];
  __syncthreads();
#pragma unroll
  for (int r = ty; r < 64; r += 4)
    dst[(long)(bx * 64 + r) * 1024 + by * 64 + tx] = (__bf16)tile[tx][r];
}

// -------- fused scores + rel-shift + softmax + PV, two strips, 3 barriers --
#define QSTR 2056                         // strip row stride (f16 elems)
#define SM_SQ (16 * QSTR * 2)             // 65792 per strip
#define FUSED_SMEM (2 * SM_SQ)            // 131584 B -> 1 block/CU

__global__ void __launch_bounds__(1024) fused_k(const __bf16* __restrict__ qb,
                                                const __bf16* __restrict__ qrr,
                                                const __bf16* __restrict__ kb,
                                                const _Float16* __restrict__ vt,
                                                const __bf16* __restrict__ rb,
                                                const float* __restrict__ cb,
                                                __bf16* __restrict__ attnb) {
  extern __shared__ char smem[];
  _Float16* qkS = (_Float16*)smem;            // qk + cb, f16 [16][QSTR]
  _Float16* xS  = (_Float16*)(smem + SM_SQ);  // shifted x,  f16 [16][QSTR]

  const int t = threadIdx.x;
  const int wave = t >> 6, lane = t & 63, lr = lane & 15, lq = lane >> 4;
  const int z  = blockIdx.x >> 7;
  const int i0 = (blockIdx.x & 127) << 4;
  const int b = z >> 4, h = z & 15;
  const bool early = (i0 <= 1023);
  const int astart = early ? i0 + 1 : i0;
  const int a  = astart + lr;    // x-row this lane owns (x-MFMA D col)
  const int ab = a - i0;         // 0..16
  const int prow = ab & 15;      // physical xS row (rows i0 and i0+16 share 0)

  // B-frags: q rows i0..i0+15, qrr rows astart..astart+15
  bf16x8 bq0, bq1, br0, br1;
  {
    const __bf16* qp = qb + (((long)z * 2048 + i0 + lr) << 6) + lq * 8;
    bq0 = *(const bf16x8*)qp; bq1 = *(const bf16x8*)(qp + 32);
    const __bf16* rp = qrr + (((long)z * 2048 + astart + lr) << 6) + lq * 8;
    br0 = *(const bf16x8*)rp; br1 = *(const bf16x8*)(rp + 32);
  }

  const __bf16* kbz = kb + (((long)z * 2048) << 6);
  const __bf16* rbh = rb + (((long)h * 2048) << 6);
  const float* cbz = cb + (long)z * 2048;

  // P12: qk MFMA (+cb fold) -> qkS  AND  x MFMA -> xS, one phase, no RMW.
  // qk D: row(lq*4+g)=key-local, col(lr)=q-row.
  // x  D: row(lq*4+g)=pos m,     col(lr)=x-row a.  Shifted col j=(m+a+1)&2047:
  //   sum>=2048 -> tail (read by strip row a), else head (read by row a-1).
  // Mask: row a=i0+16 keeps only head; row a=i0 keeps only tail.
#pragma unroll 2
  for (int s16 = 0; s16 < 8; s16++) {
    int n0 = wave * 128 + s16 * 16;
    const __bf16* ap = kbz + ((long)(n0 + lr) << 6) + lq * 8;
    bf16x8 a0 = *(const bf16x8*)ap, a1 = *(const bf16x8*)(ap + 32);
    const __bf16* rp2 = rbh + ((long)(n0 + lr) << 6) + lq * 8;
    bf16x8 r0 = *(const bf16x8*)rp2, r1 = *(const bf16x8*)(rp2 + 32);
    float4 cbv = *(const float4*)(cbz + n0 + lq * 4);
    floatx4 acc{0.f, 0.f, 0.f, 0.f}, ax{0.f, 0.f, 0.f, 0.f};
    acc = __builtin_amdgcn_mfma_f32_16x16x32_bf16(a0, bq0, acc, 0, 0, 0);
    acc = __builtin_amdgcn_mfma_f32_16x16x32_bf16(a1, bq1, acc, 0, 0, 0);
    ax  = __builtin_amdgcn_mfma_f32_16x16x32_bf16(r0, br0, ax, 0, 0, 0);
    ax  = __builtin_amdgcn_mfma_f32_16x16x32_bf16(r1, br1, ax, 0, 0, 0);
    f16x4 st;
    st[0] = (_Float16)(acc[0] * 0.125f + cbv.x);
    st[1] = (_Float16)(acc[1] * 0.125f + cbv.y);
    st[2] = (_Float16)(acc[2] * 0.125f + cbv.z);
    st[3] = (_Float16)(acc[3] * 0.125f + cbv.w);
    *(f16x4*)&qkS[lr * QSTR + n0 + lq * 4] = st;
#pragma unroll
    for (int g = 0; g < 4; g++) {
      int m = n0 + lq * 4 + g;
      int sum = m + a + 1;
      bool c1 = (sum >= 2048);            // tail (case1)
      int j = sum & 2047;
      bool skip = ((ab == 16) && c1) || ((ab == 0) && !c1);
      if (!skip) xS[prow * QSTR + j] = (_Float16)(ax[g] * 0.125f);
    }
  }

  // boundary GEMV -> xS row 0 (the 17th x-row's used part).
  // early: a=i0 tail, cols [0,i0]; late: a=i0+16 head, cols [i0+17,2048)
  {
    const int ga   = early ? i0 : i0 + 16;
    const int glen = early ? i0 + 1 : 2031 - i0;
    const int gc0  = early ? 0 : i0 + 17;
    const int gm0  = early ? 2047 - i0 : 0;
    if (glen > 0) {
      const __bf16* qrp = qrr + (((long)z * 2048 + ga) << 6);
      bf16x8 qv[8];
#pragma unroll
      for (int c8 = 0; c8 < 8; c8++) qv[c8] = *(const bf16x8*)(qrp + c8 * 8);
      for (int mi = t; mi < glen; mi += 1024) {
        const __bf16* rrp = rbh + ((long)(gm0 + mi) << 6);
        float s = 0.f;
#pragma unroll
        for (int c8 = 0; c8 < 8; c8++) {
          bf16x8 rv = *(const bf16x8*)(rrp + c8 * 8);
#pragma unroll
          for (int e = 0; e < 8; e++) s += (float)qv[c8][e] * (float)rv[e];
        }
        xS[gc0 + mi] = (_Float16)(s * 0.125f);
      }
    }
  }
  __syncthreads();   // A: both strips complete

  // V B-frag preload (64 VGPRs) — latency hidden under the exp phase
  const _Float16* vtz = vt + (((long)z) << 6) * 2048;
  f16x8 vfrag[16];
#pragma unroll
  for (int ks = 0; ks < 4; ks++)
#pragma unroll
    for (int sub = 0; sub < 4; sub++)
      vfrag[ks * 4 + sub] =
          *(const f16x8*)(vtz + (long)(sub * 16 + lr) * 2048 + wave * 128 + ks * 32 + lq * 8);

  // P3: p = exp(qk + xsel); xsel = j<=i ? xS[i][j] : (j==i+1 ? 0 : xS[i+1][j]).
  // Vectorized row reads of both strips + per-element cndmask select.
  const int r = wave, c = lane;
  const int iA = i0 + r;
  _Float16* qrow = qkS + r * QSTR;
  const _Float16* xRa = xS + r * QSTR;
  const _Float16* xRb = xS + ((r + 1) & 15) * QSTR;
  float psum = 0.f;
#pragma unroll
  for (int ii = 0; ii < 4; ii++) {
    int j0 = ii * 512 + c * 8;
    f16x8 hv = *(const f16x8*)(qrow + j0);
    f16x8 va = *(const f16x8*)(xRa + j0);
    f16x8 vb = *(const f16x8*)(xRb + j0);
    f16x8 pr;
#pragma unroll
    for (int e = 0; e < 8; e++) {
      int j = j0 + e;
      float xv = (j <= iA) ? (float)va[e] : ((j == iA + 1) ? 0.f : (float)vb[e]);
      float ev = __expf((float)hv[e] + xv);
      psum += ev;
      pr[e] = (_Float16)ev;
    }
    *(f16x8*)(qrow + j0) = pr;
  }
#pragma unroll
  for (int o = 1; o < 64; o <<= 1) psum += __shfl_xor(psum, o, 64);
  const float inv = 1.0f / psum;   // this wave's row
  __syncthreads();   // B: p~ complete, xS reads done

  // P4: PV, split-K over waves (128 keys each); V already in registers
  floatx4 oacc[4];
#pragma unroll
  for (int s = 0; s < 4; s++) oacc[s] = floatx4{0.f, 0.f, 0.f, 0.f};
#pragma unroll
  for (int ks = 0; ks < 4; ks++) {
    int kk = wave * 128 + ks * 32;
    f16x8 af = *(const f16x8*)(qkS + lr * QSTR + kk + lq * 8);
#pragma unroll
    for (int sub = 0; sub < 4; sub++)
      oacc[sub] = __builtin_amdgcn_mfma_f32_16x16x32_f16(af, vfrag[ks * 4 + sub], oacc[sub], 0, 0, 0);
  }

  // P5: fp32 partials [wave][16][64] into the xS region (dead after barrier B,
  // so no barrier needed here)
  {
    float* sPart = (float*)xS;
#pragma unroll
    for (int sub = 0; sub < 4; sub++)
#pragma unroll
      for (int g = 0; g < 4; g++)
        sPart[(wave * 16 + lq * 4 + g) * 64 + sub * 16 + lr] = oacc[sub][g];
  }
  __syncthreads();   // C: partials complete

  // P6: reduce 16 waves; normalize by this wave-row's inv
  {
    const float* sPart = (const float*)xS;
    float accO = 0.f;
#pragma unroll
    for (int w = 0; w < 16; w++) accO += sPart[(w * 16 + r) * 64 + c];
    attnb[((long)b * 2048 + i0 + r) * 1024 + h * 64 + c] = (__bf16)(accO * inv);
  }
}

extern "C" void kernel_launch(void* const* d_in, const int* in_sizes, int n_in,
                              void* d_out, int out_size, void* d_ws, size_t ws_size,
                              hipStream_t stream) {
  (void)in_sizes; (void)n_in; (void)out_size; (void)ws_size;
  const float* inputs_kv = (const float*)d_in[0];
  const float* inputs_q  = (const float*)d_in[1];
  const float* pos_embed = (const float*)d_in[2];
  const float* Wq_w = (const float*)d_in[3];
  const float* Wq_b = (const float*)d_in[4];
  const float* Wk_w = (const float*)d_in[5];
  const float* Wk_b = (const float*)d_in[6];
  const float* Wv_w = (const float*)d_in[7];
  const float* Wv_b = (const float*)d_in[8];
  const float* Wr_w = (const float*)d_in[9];
  const float* rwb  = (const float*)d_in[10];
  const float* rrb  = (const float*)d_in[11];
  const float* Wo_w = (const float*)d_in[12];
  const float* Wo_b = (const float*)d_in[13];

  char* ws = (char*)d_ws;
  const long MB = 1 << 20;
  __bf16* Wtq = (__bf16*)(ws + 0 * MB);
  __bf16* Wtk = (__bf16*)(ws + 2 * MB);
  __bf16* Wtv = (__bf16*)(ws + 4 * MB);
  __bf16* Wtr = (__bf16*)(ws + 6 * MB);
  __bf16* Wto = (__bf16*)(ws + 8 * MB);
  __bf16* qb  = (__bf16*)(ws + 10 * MB);
  __bf16* qrr = (__bf16*)(ws + 18 * MB);
  __bf16* kb  = (__bf16*)(ws + 26 * MB);
  _Float16* vt = (_Float16*)(ws + 34 * MB);
  __bf16* rb  = (__bf16*)(ws + 42 * MB);
  float*  cb  = (float*)(ws + 46 * MB);               // 256 KB
  __bf16* attnb = (__bf16*)(ws + 47 * MB);            // 8 MB bf16 attention out

  dim3 blk(256);

  tr_cvt<<<dim3(16, 16), blk, 0, stream>>>(Wq_w, Wtq);
  tr_cvt<<<dim3(16, 16), blk, 0, stream>>>(Wk_w, Wtk);
  tr_cvt<<<dim3(16, 16), blk, 0, stream>>>(Wv_w, Wtv);
  tr_cvt<<<dim3(16, 16), blk, 0, stream>>>(Wr_w, Wtr);
  tr_cvt<<<dim3(16, 16), blk, 0, stream>>>(Wo_w, Wto);

  GP p{};
  p.lda = 1024; p.ldb = 1024; p.K = 1024;

  p.A = inputs_q; p.B = Wtq; p.out1 = qb; p.out2 = qrr; p.bias = Wq_b; p.rrb = rrb;
  gemm_k<0, true><<<dim3(8, 32, 1), blk, 0, stream>>>(p);
  p.A = inputs_kv; p.B = Wtk; p.out1 = kb; p.out2 = nullptr; p.bias = Wk_b;
  gemm_k<1, true><<<dim3(8, 32, 1), blk, 0, stream>>>(p);
  p.A = inputs_kv; p.B = Wtv; p.out1h = vt; p.bias = Wv_b;
  gemm_k<2, true><<<dim3(8, 32, 1), blk, 0, stream>>>(p);
  p.A = pos_embed; p.B = Wtr; p.out1 = rb; p.bias = nullptr;
  gemm_k<3, true><<<dim3(8, 16, 1), blk, 0, stream>>>(p);

  cb_k<<<dim3(256), blk, 0, stream>>>(kb, rwb, cb);

  hipFuncSetAttribute((const void*)fused_k,
                      hipFuncAttributeMaxDynamicSharedMemorySize, FUSED_SMEM);
  fused_k<<<dim3(4096), dim3(1024), FUSED_SMEM, stream>>>(qb, qrr, kb, vt, rb, cb, attnb);

  // Output projection: d_out = attn(bf16) @ Wo + bo
  GP o{};
  o.A = attnb; o.B = Wto; o.lda = 1024; o.ldb = 1024; o.K = 1024;
  o.bias = Wo_b; o.outF = (float*)d_out;
  gemm_k<4, false><<<dim3(8, 32, 1), blk, 0, stream>>>(o);
}